// Round 9
// baseline (26.192 us; speedup 1.0000x reference)
//
#include <hip/hip_runtime.h>

#define T_IN 2048
#define UPSCALE 480
#define T_OUT (T_IN * UPSCALE)        // 983040
#define NBATCH 32
#define NTHREADS 256
#define NBLOCKS 2048
#define NTOTAL (NBLOCKS * NTHREADS)   // 524288 threads
#define ITERS 15                      // 524288*15 groups = 7864320 = total float4 groups
#define GROUPS_PER_BATCH (T_OUT / 4)  // 245760 (divisible by 64 -> no wave straddle)
#define NINTERVAL (T_IN - 1)          // 2047

__device__ __forceinline__ float signf(float x) {
    return (x > 0.f) ? 1.f : ((x < 0.f) ? -1.f : 0.f);
}

// Fritsch-Carlson edge slope (matches reference edge())
__device__ __forceinline__ float edge_slope(float dA, float dB) {
    float d = (3.f * dA - dB) * 0.5f;
    if (signf(d) != signf(dA)) {
        d = 0.f;
    } else if ((signf(dA) != signf(dB)) && (fabsf(d) > 3.f * fabsf(dA))) {
        d = 3.f * dA;
    }
    return d;
}

// Harmonic-mean interior slope via fast v_rcp_f32 (rel err ~1e-7).
__device__ __forceinline__ float interior_slope(float a, float b) {
    float p = a * b;
    float r = __builtin_amdgcn_rcpf(a + b);
    return (p > 0.f) ? 2.f * p * r : 0.f;
}

// R8 math verbatim; ONE change: blocked -> grid-stride interleaved output
// mapping. At any instant the chip writes one contiguous ~8.4 MB sweeping
// window (like the 6.85 TB/s fill kernels) instead of 2048 scattered 60 KB
// chunks -> HBM row-buffer locality.
__global__ __launch_bounds__(NTHREADS) void pchip_upsample_kernel(
    const float* __restrict__ x, float* __restrict__ out)
{
    const int gid = blockIdx.x * NTHREADS + threadIdx.x;   // 0..524287
    const float STEP = (float)(T_IN - 1) / (float)(T_OUT - 1);

    float4* __restrict__ outv = (float4*)out;

    #pragma unroll 3
    for (int it = 0; it < ITERS; ++it) {
        const int g  = gid + it * NTOTAL;          // global float4-group index
        const int b  = g / GROUPS_PER_BATCH;       // batch (magic-mul)
        const int gb = g - b * GROUPS_PER_BATCH;   // group within batch
        const int j0 = gb * 4;                     // output index within batch

        const float* __restrict__ y = x + (size_t)b * T_IN;

        float t0 = (float)j0 * STEP;
        int idx = (int)t0;
        idx = idx > (NINTERVAL - 1) ? (NINTERVAL - 1) : idx;
        float s0 = t0 - (float)idx;

        const int im1 = (idx > 0) ? idx - 1 : 0;
        const int ip2 = (idx < T_IN - 2) ? idx + 2 : T_IN - 1;

        // near-broadcast loads, L1/L2-resident
        float ym1 = y[im1];
        float y0  = y[idx];
        float y1  = y[idx + 1];
        float y2  = y[ip2];

        float dl = y0 - ym1;   // delta[idx-1]
        float dc = y1 - y0;    // delta[idx]
        float dr = y2 - y1;    // delta[idx+1]

        float d0 = interior_slope(dl, dc);
        if (idx == 0) d0 = edge_slope(dc, dr);
        float d1 = interior_slope(dc, dr);
        if (idx == NINTERVAL - 1) d1 = edge_slope(dc, dl);

        // v(s) = c0 + c1*s + c2*s^2 + c3*s^3
        float c0 = y0;
        float c1 = d0;
        float c2 = __builtin_fmaf(3.f, dc, -2.f * d0) - d1;
        float c3 = (d0 + d1) - 2.f * dc;

        float4 r;
        float s = s0;
        r.x = __builtin_fmaf(__builtin_fmaf(__builtin_fmaf(c3, s, c2), s, c1), s, c0); s += STEP;
        r.y = __builtin_fmaf(__builtin_fmaf(__builtin_fmaf(c3, s, c2), s, c1), s, c0); s += STEP;
        r.z = __builtin_fmaf(__builtin_fmaf(__builtin_fmaf(c3, s, c2), s, c1), s, c0); s += STEP;
        r.w = __builtin_fmaf(__builtin_fmaf(__builtin_fmaf(c3, s, c2), s, c1), s, c0);

        // flat store: b*T_OUT + j0 == g*4 exactly (batches contiguous)
        outv[g] = r;
    }
}

extern "C" void kernel_launch(void* const* d_in, const int* in_sizes, int n_in,
                              void* d_out, int out_size, void* d_ws, size_t ws_size,
                              hipStream_t stream) {
    (void)d_ws; (void)ws_size; (void)n_in; (void)out_size; (void)in_sizes;
    const float* x = (const float*)d_in[0];
    float* out = (float*)d_out;

    pchip_upsample_kernel<<<NBLOCKS, NTHREADS, 0, stream>>>(x, out);
}